// Round 13
// baseline (369.543 us; speedup 1.0000x reference)
//
#include <hip/hip_runtime.h>
#include <hip/hip_bf16.h>

typedef unsigned short u16;
using short8  = __attribute__((ext_vector_type(8))) short;
using floatx4 = __attribute__((ext_vector_type(4))) float;

__device__ inline u16 f2bu(float f) {
    __hip_bfloat16 h = __float2bfloat16(f);
    return __builtin_bit_cast(u16, h);
}
__device__ inline float b2f(u16 u) {
    unsigned v = (unsigned)u << 16;
    return __builtin_bit_cast(float, v);
}
__device__ inline float gelu_f(float v) {
    float u = 1.5957691216f * (v + 0.044715f * v * v * v);
    return v / (1.f + __expf(-u));
}

// async global->LDS, 16B per lane; LDS dest = wave-uniform base + lane*16.
__device__ inline void load16(const u16* g, u16* l) {
    __builtin_amdgcn_global_load_lds(
        (const __attribute__((address_space(1))) void*)g,
        (__attribute__((address_space(3))) void*)l, 16, 0, 0);
}

// ---------------------------------------------------------------- fused prep:
// blocks [0,8192): LN1 row; blocks [8192,15104): fp32->bf16 weight cvt,
// segmented over {qkv_w, proj_w, fc1_w, fc2_w}. All segment sizes are exact
// multiples of 256 -> block-uniform branches.
__global__ __launch_bounds__(256) void prep_fused(
    const float* __restrict__ x, const float* __restrict__ g,
    const float* __restrict__ b, u16* __restrict__ h,
    const float4* __restrict__ qkvw, ushort4* __restrict__ wq,
    const float4* __restrict__ projw, ushort4* __restrict__ wp,
    const float4* __restrict__ fc1w, ushort4* __restrict__ w1,
    const float4* __restrict__ fc2w, ushort4* __restrict__ w2)
{
    int blk = blockIdx.x;
    int tid = threadIdx.x;
    if (blk < 8192) {
        const float* xr = x + (size_t)blk * 768;
        float v0 = xr[tid], v1 = xr[tid + 256], v2 = xr[tid + 512];
        float s = v0 + v1 + v2;
        float ss = v0 * v0 + v1 * v1 + v2 * v2;
        for (int off = 1; off < 64; off <<= 1) {
            s  += __shfl_xor(s, off, 64);
            ss += __shfl_xor(ss, off, 64);
        }
        __shared__ float as[4], ass[4];
        int wave = tid >> 6, lane = tid & 63;
        if (lane == 0) { as[wave] = s; ass[wave] = ss; }
        __syncthreads();
        s  = as[0] + as[1] + as[2] + as[3];
        ss = ass[0] + ass[1] + ass[2] + ass[3];
        float mu  = s * (1.0f / 768.0f);
        float var = ss * (1.0f / 768.0f) - mu * mu;
        float rs  = rsqrtf(var + 1e-5f);
        u16* orow = h + (size_t)blk * 768;
        orow[tid]       = f2bu((v0 - mu) * rs * g[tid]       + b[tid]);
        orow[tid + 256] = f2bu((v1 - mu) * rs * g[tid + 256] + b[tid + 256]);
        orow[tid + 512] = f2bu((v2 - mu) * rs * g[tid + 512] + b[tid + 512]);
    } else {
        int i = (blk - 8192) * 256 + tid;
        const float4* src; ushort4* dst;
        if (i < 442368)                     { src = qkvw;  dst = wq; }
        else if (i < 442368 + 147456)       { src = projw; dst = wp; i -= 442368; }
        else if (i < 442368 + 147456 + 589824) { src = fc1w; dst = w1; i -= 442368 + 147456; }
        else                                { src = fc2w;  dst = w2; i -= 442368 + 147456 + 589824; }
        float4 f = src[i];
        ushort4 r;
        r.x = f2bu(f.x); r.y = f2bu(f.y); r.z = f2bu(f.z); r.w = f2bu(f.w);
        dst[i] = r;
    }
}

// ---------------------------------------------------------------- layernorm (row=768)
__global__ __launch_bounds__(256) void layernorm_bf16(
    const float* __restrict__ x, const float* __restrict__ g,
    const float* __restrict__ b, u16* __restrict__ out)
{
    int row = blockIdx.x;
    int tid = threadIdx.x;
    const float* xr = x + (size_t)row * 768;
    float v0 = xr[tid], v1 = xr[tid + 256], v2 = xr[tid + 512];
    float s = v0 + v1 + v2;
    float ss = v0 * v0 + v1 * v1 + v2 * v2;
    for (int off = 1; off < 64; off <<= 1) {
        s  += __shfl_xor(s, off, 64);
        ss += __shfl_xor(ss, off, 64);
    }
    __shared__ float as[4], ass[4];
    int wave = tid >> 6, lane = tid & 63;
    if (lane == 0) { as[wave] = s; ass[wave] = ss; }
    __syncthreads();
    s  = as[0] + as[1] + as[2] + as[3];
    ss = ass[0] + ass[1] + ass[2] + ass[3];
    float mu  = s * (1.0f / 768.0f);
    float var = ss * (1.0f / 768.0f) - mu * mu;
    float rs  = rsqrtf(var + 1e-5f);
    u16* orow = out + (size_t)row * 768;
    orow[tid]       = f2bu((v0 - mu) * rs * g[tid]       + b[tid]);
    orow[tid + 256] = f2bu((v1 - mu) * rs * g[tid + 256] + b[tid + 256]);
    orow[tid + 512] = f2bu((v2 - mu) * rs * g[tid + 512] + b[tid + 512]);
}

// ---------------------------------------------------------------- split-K reduce (4 partials)
// out = out + bias + P0 + P1 + P2 + P3   (fp32), over 8192x768
__global__ __launch_bounds__(256) void red4(
    const ushort4* __restrict__ P0, const ushort4* __restrict__ P1,
    const ushort4* __restrict__ P2, const ushort4* __restrict__ P3,
    const float* __restrict__ bias, float4* __restrict__ out)
{
    int i = blockIdx.x * 256 + threadIdx.x;
    int col = (i % 192) * 4;
    ushort4 a = P0[i], b = P1[i], c = P2[i], d = P3[i];
    float4 o = out[i];
    o.x += bias[col + 0] + b2f(a.x) + b2f(b.x) + b2f(c.x) + b2f(d.x);
    o.y += bias[col + 1] + b2f(a.y) + b2f(b.y) + b2f(c.y) + b2f(d.y);
    o.z += bias[col + 2] + b2f(a.z) + b2f(b.z) + b2f(c.z) + b2f(d.z);
    o.w += bias[col + 3] + b2f(a.w) + b2f(b.w) + b2f(c.w) + b2f(d.w);
    out[i] = o;
}

// ---------------------------------------------------------------- fused proj-reduce + LN2
__global__ __launch_bounds__(256) void red2_ln(
    const u16* __restrict__ P0, const u16* __restrict__ P1,
    const float* __restrict__ bias, const float* __restrict__ x,
    float* __restrict__ out,
    const float* __restrict__ g, const float* __restrict__ bb,
    u16* __restrict__ h)
{
    int row = blockIdx.x;
    int tid = threadIdx.x;
    size_t base = (size_t)row * 768;
    float v[3];
    float s = 0.f, ss = 0.f;
    #pragma unroll
    for (int j = 0; j < 3; ++j) {
        int col = tid + j * 256;
        size_t idx = base + col;
        float o = x[idx] + bias[col] + b2f(P0[idx]) + b2f(P1[idx]);
        out[idx] = o;
        v[j] = o;
        s += o; ss += o * o;
    }
    for (int off = 1; off < 64; off <<= 1) {
        s  += __shfl_xor(s, off, 64);
        ss += __shfl_xor(ss, off, 64);
    }
    __shared__ float as[4], ass[4];
    int wave = tid >> 6, lane = tid & 63;
    if (lane == 0) { as[wave] = s; ass[wave] = ss; }
    __syncthreads();
    s  = as[0] + as[1] + as[2] + as[3];
    ss = ass[0] + ass[1] + ass[2] + ass[3];
    float mu  = s * (1.0f / 768.0f);
    float var = ss * (1.0f / 768.0f) - mu * mu;
    float rs  = rsqrtf(var + 1e-5f);
    #pragma unroll
    for (int j = 0; j < 3; ++j) {
        int col = tid + j * 256;
        h[base + col] = f2bu((v[j] - mu) * rs * g[col] + bb[col]);
    }
}

// ---------------------------------------------------------------- GEMM 128x128, BK=64
// r3 config VERBATIM (measured best: FC1 65.7us, occ 49%, 0 conflicts).
// act: 0=none, 1=gelu, 2=scale cols<768 by 0.125 (Q pre-scale for attn).
// Charted and rejected: dbuf-drain (r1), BK32+vmcnt (r2), BM256 (r4),
// dbuf+counted-vmcnt (r5), 16x acc[2][2] (r6), 4x acc[4][4]+LB (r7),
// fp32-atomic split-K epilogue (r11: MfmaUtil 25->15, +9us).
__global__ __launch_bounds__(512, 4) void gemm_k64(
    const u16* __restrict__ A, int lda,
    const u16* __restrict__ B, int ldb,
    int K,
    const float* __restrict__ bias,
    const float* __restrict__ res,
    float* __restrict__ outf, u16* __restrict__ outb,
    u16* __restrict__ parts, size_t pstride,
    int ldc, int act, int splits)
{
    __shared__ u16 lsa[128 * 64];
    __shared__ u16 lsb[128 * 64];

    int tid  = threadIdx.x;
    int wave = tid >> 6, lane = tid & 63;
    int quad = lane >> 4, l16 = lane & 15;
    int wrow = (wave >> 1) * 32;     // 4 wave-rows x 32 rows
    int wcol = (wave & 1) * 64;      // 2 wave-cols x 64 cols

    int gx = gridDim.x;
    int nblk = gx * gridDim.y;
    int flat = blockIdx.y * gx + blockIdx.x;
    int d = (flat & 7) * (nblk >> 3) + (flat >> 3);
    int m0 = (d / gx) * 128, n0 = (d % gx) * 128;

    int Kper = K / splits;
    int kbeg = blockIdx.z * Kper;

    floatx4 acc[2][4];
    #pragma unroll
    for (int i = 0; i < 2; ++i)
        #pragma unroll
        for (int j = 0; j < 4; ++j)
            acc[i][j] = (floatx4){0.f, 0.f, 0.f, 0.f};

    int rsub = lane >> 3;
    int gc   = (lane & 7) ^ rsub;
    const u16* gA[2];
    const u16* gB[2];
    #pragma unroll
    for (int j = 0; j < 2; ++j) {
        int r = (j * 8 + wave) * 8 + rsub;
        gA[j] = A + (size_t)(m0 + r) * lda + kbeg + gc * 8;
        gB[j] = B + (size_t)(n0 + r) * ldb + kbeg + gc * 8;
    }

    int xq0 = ((quad)     ^ (l16 & 7)) * 8;
    int xq1 = ((quad + 4) ^ (l16 & 7)) * 8;

    for (int k0 = 0; k0 < Kper; k0 += 64) {
        __syncthreads();
        #pragma unroll
        for (int j = 0; j < 2; ++j) { load16(gA[j], &lsa[(j * 8 + wave) * 512]); gA[j] += 64; }
        #pragma unroll
        for (int j = 0; j < 2; ++j) { load16(gB[j], &lsb[(j * 8 + wave) * 512]); gB[j] += 64; }
        __syncthreads();

        short8 af[2], bfr[4];
        #pragma unroll
        for (int rb = 0; rb < 2; ++rb) af[rb]  = *(const short8*)&lsa[(wrow + rb * 16 + l16) * 64 + xq0];
        #pragma unroll
        for (int cb = 0; cb < 4; ++cb) bfr[cb] = *(const short8*)&lsb[(wcol + cb * 16 + l16) * 64 + xq0];
        #pragma unroll
        for (int rb = 0; rb < 2; ++rb)
            #pragma unroll
            for (int cb = 0; cb < 4; ++cb)
                acc[rb][cb] = __builtin_amdgcn_mfma_f32_16x16x32_bf16(af[rb], bfr[cb], acc[rb][cb], 0, 0, 0);
        #pragma unroll
        for (int rb = 0; rb < 2; ++rb) af[rb]  = *(const short8*)&lsa[(wrow + rb * 16 + l16) * 64 + xq1];
        #pragma unroll
        for (int cb = 0; cb < 4; ++cb) bfr[cb] = *(const short8*)&lsb[(wcol + cb * 16 + l16) * 64 + xq1];
        #pragma unroll
        for (int rb = 0; rb < 2; ++rb)
            #pragma unroll
            for (int cb = 0; cb < 4; ++cb)
                acc[rb][cb] = __builtin_amdgcn_mfma_f32_16x16x32_bf16(af[rb], bfr[cb], acc[rb][cb], 0, 0, 0);
    }

    u16* pdst = (splits > 1) ? parts + (size_t)blockIdx.z * pstride : nullptr;
    #pragma unroll
    for (int rb = 0; rb < 2; ++rb)
        #pragma unroll
        for (int cb = 0; cb < 4; ++cb)
            #pragma unroll
            for (int r = 0; r < 4; ++r) {
                int row = m0 + wrow + rb * 16 + quad * 4 + r;
                int col = n0 + wcol + cb * 16 + l16;
                float v = acc[rb][cb][r];
                if (splits > 1) {
                    pdst[(size_t)row * ldc + col] = f2bu(v);
                } else {
                    v += bias[col];
                    if (res) v += res[(size_t)row * ldc + col];
                    if (act == 1) v = gelu_f(v);
                    else if (act == 2 && col < 768) v *= 0.125f;   // Q pre-scale (exact: pow2)
                    if (outf) outf[(size_t)row * ldc + col] = v;
                    else      outb[(size_t)row * ldc + col] = f2bu(v);
                }
            }
}

// ---------------------------------------------------------------- fused attention
// qkv: bf16 [8*1024, 2304] with Q pre-scaled by 1/8; o: bf16 [8*1024, 768]
// grid (8 q-blocks of 128 rows, 96 b*h), block 256; wave = 32 q-rows.
__global__ __launch_bounds__(256) void attn_fused(
    const u16* __restrict__ qkv, u16* __restrict__ o)
{
    const int N = 1024, C3 = 2304;
    int qb = blockIdx.x;
    int bh = blockIdx.y;
    int b = bh / 12, h = bh % 12;
    int tid = threadIdx.x, wave = tid >> 6, lane = tid & 63;
    int quad = lane >> 4, l16 = lane & 15;

    __shared__ u16 lk[64 * 64];       // K tile, XOR-swizzled [key][dchunk]
    __shared__ u16 lvt[64][72];       // V^T tile [d][key]
    __shared__ u16 lp[4][32][72];     // per-wave P [qrow(32)][key(64)]

    const size_t base = (size_t)b * N * C3;
    int q0 = qb * 128 + wave * 32;

    short8 qa[2][2];
    #pragma unroll
    for (int rb = 0; rb < 2; ++rb)
        #pragma unroll
        for (int ch = 0; ch < 2; ++ch)
            qa[rb][ch] = *(const short8*)&qkv[base + (size_t)(q0 + rb * 16 + l16) * C3 + h * 64 + ch * 32 + quad * 8];

    floatx4 oacc[2][4];
    #pragma unroll
    for (int i = 0; i < 2; ++i)
        #pragma unroll
        for (int j = 0; j < 4; ++j) oacc[i][j] = (floatx4){0.f, 0.f, 0.f, 0.f};
    float lsum[2][4] = {};

    for (int kt = 0; kt < N; kt += 64) {
        __syncthreads();
        #pragma unroll
        for (int i = 0; i < 2; ++i) {
            int idx = i * 2048 + wave * 512 + lane * 8;
            int r = idx >> 6;
            int gc = (lane & 7) ^ (r & 7);
            load16(&qkv[base + (size_t)(kt + r) * C3 + 768 + h * 64 + gc * 8], &lk[idx]);
        }
        {
            // packed V^T staging: thread owns keys {2kp, 2kp+1}, 8 d-values each;
            // writes 8 x b32 pairs (consecutive keys are adjacent u16 in a row).
            int kp = tid & 31;
            int dbase = (tid >> 5) * 8;
            const u16* vp0 = &qkv[base + (size_t)(kt + 2 * kp) * C3 + 1536 + h * 64 + dbase];
            const u16* vp1 = vp0 + C3;
            uint4 va = *(const uint4*)vp0;
            uint4 vb = *(const uint4*)vp1;
            const u16* e0 = (const u16*)&va;
            const u16* e1 = (const u16*)&vb;
            #pragma unroll
            for (int i = 0; i < 8; ++i) {
                unsigned pk = (unsigned)e0[i] | ((unsigned)e1[i] << 16);
                *(unsigned*)&lvt[dbase + i][2 * kp] = pk;
            }
        }
        __syncthreads();

        // S = Q K^T (Q pre-scaled) ; P = exp(S)
        #pragma unroll
        for (int kb = 0; kb < 4; ++kb) {
            int R = kb * 16 + l16;
            short8 b0 = *(short8*)&lk[R * 64 + ((quad ^ (R & 7)) * 8)];
            short8 b1 = *(short8*)&lk[R * 64 + (((quad + 4) ^ (R & 7)) * 8)];
            #pragma unroll
            for (int rb = 0; rb < 2; ++rb) {
                floatx4 c = (floatx4){0.f, 0.f, 0.f, 0.f};
                c = __builtin_amdgcn_mfma_f32_16x16x32_bf16(qa[rb][0], b0, c, 0, 0, 0);
                c = __builtin_amdgcn_mfma_f32_16x16x32_bf16(qa[rb][1], b1, c, 0, 0, 0);
                #pragma unroll
                for (int r = 0; r < 4; ++r) {
                    float p = __expf(c[r]);
                    lsum[rb][r] += p;
                    lp[wave][rb * 16 + quad * 4 + r][kb * 16 + l16] = f2bu(p);
                }
            }
        }

        // O += P V   (per-wave lp slice: same-wave RAW ordered by lgkmcnt)
        short8 pa[2][2];
        #pragma unroll
        for (int rb = 0; rb < 2; ++rb) {
            pa[rb][0] = *(short8*)&lp[wave][rb * 16 + l16][quad * 8];
            pa[rb][1] = *(short8*)&lp[wave][rb * 16 + l16][32 + quad * 8];
        }
        #pragma unroll
        for (int db = 0; db < 4; ++db) {
            short8 vb0 = *(short8*)&lvt[db * 16 + l16][quad * 8];
            short8 vb1 = *(short8*)&lvt[db * 16 + l16][32 + quad * 8];
            #pragma unroll
            for (int rb = 0; rb < 2; ++rb) {
                oacc[rb][db] = __builtin_amdgcn_mfma_f32_16x16x32_bf16(pa[rb][0], vb0, oacc[rb][db], 0, 0, 0);
                oacc[rb][db] = __builtin_amdgcn_mfma_f32_16x16x32_bf16(pa[rb][1], vb1, oacc[rb][db], 0, 0, 0);
            }
        }
    }

    #pragma unroll
    for (int rb = 0; rb < 2; ++rb)
        #pragma unroll
        for (int r = 0; r < 4; ++r)
            for (int off = 1; off < 16; off <<= 1)
                lsum[rb][r] += __shfl_xor(lsum[rb][r], off, 64);

    #pragma unroll
    for (int rb = 0; rb < 2; ++rb)
        #pragma unroll
        for (int db = 0; db < 4; ++db)
            #pragma unroll
            for (int r = 0; r < 4; ++r) {
                int row = q0 + rb * 16 + quad * 4 + r;
                int col = h * 64 + db * 16 + l16;
                o[(size_t)(b * N + row) * 768 + col] = f2bu(oacc[rb][db][r] / lsum[rb][r]);
            }
}

// ---------------------------------------------------------------- launch
extern "C" void kernel_launch(void* const* d_in, const int* in_sizes, int n_in,
                              void* d_out, int out_size, void* d_ws, size_t ws_size,
                              hipStream_t stream) {
    const float* x      = (const float*)d_in[0];
    const float* n1g    = (const float*)d_in[1];
    const float* n1b    = (const float*)d_in[2];
    const float* qkv_w  = (const float*)d_in[3];
    const float* qkv_b  = (const float*)d_in[4];
    const float* proj_w = (const float*)d_in[5];
    const float* proj_b = (const float*)d_in[6];
    const float* n2g    = (const float*)d_in[7];
    const float* n2b    = (const float*)d_in[8];
    const float* fc1_w  = (const float*)d_in[9];
    const float* fc1_b  = (const float*)d_in[10];
    const float* fc2_w  = (const float*)d_in[11];
    const float* fc2_b  = (const float*)d_in[12];
    float* out = (float*)d_out;

    const int T = 8192;
    char* ws = (char*)d_ws;
    u16* w_qkv  = (u16*)ws;               ws += (size_t)2304 * 768 * 2;
    u16* w_proj = (u16*)ws;               ws += (size_t)768 * 768 * 2;
    u16* w_fc1  = (u16*)ws;               ws += (size_t)3072 * 768 * 2;
    u16* w_fc2  = (u16*)ws;               ws += (size_t)768 * 3072 * 2;
    u16* h_buf  = (u16*)ws;               ws += (size_t)T * 768 * 2;
    u16* qkvbuf = (u16*)ws;               ws += (size_t)T * 2304 * 2;
    u16* o_buf  = (u16*)ws;               ws += (size_t)T * 768 * 2;
    u16* pbuf   = (u16*)ws;               ws += (size_t)T * 768 * 2;   // proj partial #1; FC2 partial slot 0
    /* 3 more FC2 partial slots, contiguous after pbuf (stride T*768) */
    ws += (size_t)T * 768 * 2 * 3;
    u16* fc1out = qkvbuf;   // spans qkvbuf+o_buf (both dead at FC1 time)
    bool do_split = (size_t)(ws - (char*)d_ws) <= ws_size;
    size_t pstr = (size_t)(pbuf - h_buf);  // proj: partial0(h_buf) -> partial1(pbuf)
    size_t pstr4 = (size_t)T * 768;        // FC2: 4 contiguous slots from pbuf

    // fused: LN1 (8192 blocks) + all 4 weight cvts (6912 blocks)
    prep_fused<<<dim3(15104), 256, 0, stream>>>(
        x, n1g, n1b, h_buf,
        (const float4*)qkv_w,  (ushort4*)w_qkv,
        (const float4*)proj_w, (ushort4*)w_proj,
        (const float4*)fc1_w,  (ushort4*)w_fc1,
        (const float4*)fc2_w,  (ushort4*)w_fc2);

    // QKV (act=2: pre-scale Q columns by 1/8 for attention)
    gemm_k64<<<dim3(2304 / 128, T / 128), 512, 0, stream>>>(
        h_buf, 768, w_qkv, 768, 768, qkv_b, nullptr, nullptr, qkvbuf, nullptr, 0, 2304, 2, 1);
    // attention (128 q-rows/block)
    attn_fused<<<dim3(8, 96), 256, 0, stream>>>(qkvbuf, o_buf);
    // proj split-K=2 -> partials h_buf,pbuf; fused reduce+residual+LN2 -> out(fp32) + h(bf16)
    if (do_split) {
        gemm_k64<<<dim3(768 / 128, T / 128, 2), 512, 0, stream>>>(
            o_buf, 768, w_proj, 768, 768, proj_b, nullptr, nullptr, nullptr,
            h_buf, pstr, 768, 0, 2);
        red2_ln<<<dim3(T), 256, 0, stream>>>(
            h_buf, pbuf, proj_b, x, out, n2g, n2b, h_buf);
    } else {
        gemm_k64<<<dim3(768 / 128, T / 128), 512, 0, stream>>>(
            o_buf, 768, w_proj, 768, 768, proj_b, x, out, nullptr, nullptr, 0, 768, 0, 1);
        layernorm_bf16<<<dim3(T), 256, 0, stream>>>(out, n2g, n2b, h_buf);
    }
    // FC1 + GELU
    gemm_k64<<<dim3(3072 / 128, T / 128), 512, 0, stream>>>(
        h_buf, 768, w_fc1, 768, 768, fc1_b, nullptr, nullptr, fc1out, nullptr, 0, 3072, 1, 1);
    // FC2 split-K=4: 6x64x4 = 1536 blocks = exactly 3 resident generations
    // (512 slots at 2 blocks/CU) -> depth 36 K-steps vs split-2's 48 (1.5-gen
    // tail, r4-measured mechanism). Partials in 4 contiguous slots from pbuf
    // (h_buf holds LN2 output, still live as FC1's A - not used here).
    if (do_split) {
        gemm_k64<<<dim3(768 / 128, T / 128, 4), 512, 0, stream>>>(
            fc1out, 3072, w_fc2, 3072, 3072, fc2_b, nullptr, nullptr, nullptr,
            pbuf, pstr4, 768, 0, 4);
        red4<<<dim3(T * 768 / 4 / 256), 256, 0, stream>>>(
            (const ushort4*)pbuf,
            (const ushort4*)(pbuf + pstr4),
            (const ushort4*)(pbuf + 2 * pstr4),
            (const ushort4*)(pbuf + 3 * pstr4),
            fc2_b, (float4*)out);
    } else {
        gemm_k64<<<dim3(768 / 128, T / 128), 512, 0, stream>>>(
            fc1out, 3072, w_fc2, 3072, 3072, fc2_b, out, out, nullptr, nullptr, 0, 768, 0, 1);
    }
}

// Round 14
// 344.224 us; speedup vs baseline: 1.0736x; 1.0736x over previous
//
#include <hip/hip_runtime.h>
#include <hip/hip_bf16.h>

typedef unsigned short u16;
using short8  = __attribute__((ext_vector_type(8))) short;
using floatx4 = __attribute__((ext_vector_type(4))) float;

__device__ inline u16 f2bu(float f) {
    __hip_bfloat16 h = __float2bfloat16(f);
    return __builtin_bit_cast(u16, h);
}
__device__ inline float b2f(u16 u) {
    unsigned v = (unsigned)u << 16;
    return __builtin_bit_cast(float, v);
}
__device__ inline float gelu_f(float v) {
    float u = 1.5957691216f * (v + 0.044715f * v * v * v);
    return v / (1.f + __expf(-u));
}

// async global->LDS, 16B per lane; LDS dest = wave-uniform base + lane*16.
__device__ inline void load16(const u16* g, u16* l) {
    __builtin_amdgcn_global_load_lds(
        (const __attribute__((address_space(1))) void*)g,
        (__attribute__((address_space(3))) void*)l, 16, 0, 0);
}

// ---------------------------------------------------------------- fused prep:
// blocks [0,8192): LN1 row; blocks [8192,15104): fp32->bf16 weight cvt,
// segmented over {qkv_w, proj_w, fc1_w, fc2_w}. All segment sizes are exact
// multiples of 256 -> block-uniform branches.
__global__ __launch_bounds__(256) void prep_fused(
    const float* __restrict__ x, const float* __restrict__ g,
    const float* __restrict__ b, u16* __restrict__ h,
    const float4* __restrict__ qkvw, ushort4* __restrict__ wq,
    const float4* __restrict__ projw, ushort4* __restrict__ wp,
    const float4* __restrict__ fc1w, ushort4* __restrict__ w1,
    const float4* __restrict__ fc2w, ushort4* __restrict__ w2)
{
    int blk = blockIdx.x;
    int tid = threadIdx.x;
    if (blk < 8192) {
        const float* xr = x + (size_t)blk * 768;
        float v0 = xr[tid], v1 = xr[tid + 256], v2 = xr[tid + 512];
        float s = v0 + v1 + v2;
        float ss = v0 * v0 + v1 * v1 + v2 * v2;
        for (int off = 1; off < 64; off <<= 1) {
            s  += __shfl_xor(s, off, 64);
            ss += __shfl_xor(ss, off, 64);
        }
        __shared__ float as[4], ass[4];
        int wave = tid >> 6, lane = tid & 63;
        if (lane == 0) { as[wave] = s; ass[wave] = ss; }
        __syncthreads();
        s  = as[0] + as[1] + as[2] + as[3];
        ss = ass[0] + ass[1] + ass[2] + ass[3];
        float mu  = s * (1.0f / 768.0f);
        float var = ss * (1.0f / 768.0f) - mu * mu;
        float rs  = rsqrtf(var + 1e-5f);
        u16* orow = h + (size_t)blk * 768;
        orow[tid]       = f2bu((v0 - mu) * rs * g[tid]       + b[tid]);
        orow[tid + 256] = f2bu((v1 - mu) * rs * g[tid + 256] + b[tid + 256]);
        orow[tid + 512] = f2bu((v2 - mu) * rs * g[tid + 512] + b[tid + 512]);
    } else {
        int i = (blk - 8192) * 256 + tid;
        const float4* src; ushort4* dst;
        if (i < 442368)                     { src = qkvw;  dst = wq; }
        else if (i < 442368 + 147456)       { src = projw; dst = wp; i -= 442368; }
        else if (i < 442368 + 147456 + 589824) { src = fc1w; dst = w1; i -= 442368 + 147456; }
        else                                { src = fc2w;  dst = w2; i -= 442368 + 147456 + 589824; }
        float4 f = src[i];
        ushort4 r;
        r.x = f2bu(f.x); r.y = f2bu(f.y); r.z = f2bu(f.z); r.w = f2bu(f.w);
        dst[i] = r;
    }
}

// ---------------------------------------------------------------- layernorm (row=768)
__global__ __launch_bounds__(256) void layernorm_bf16(
    const float* __restrict__ x, const float* __restrict__ g,
    const float* __restrict__ b, u16* __restrict__ out)
{
    int row = blockIdx.x;
    int tid = threadIdx.x;
    const float* xr = x + (size_t)row * 768;
    float v0 = xr[tid], v1 = xr[tid + 256], v2 = xr[tid + 512];
    float s = v0 + v1 + v2;
    float ss = v0 * v0 + v1 * v1 + v2 * v2;
    for (int off = 1; off < 64; off <<= 1) {
        s  += __shfl_xor(s, off, 64);
        ss += __shfl_xor(ss, off, 64);
    }
    __shared__ float as[4], ass[4];
    int wave = tid >> 6, lane = tid & 63;
    if (lane == 0) { as[wave] = s; ass[wave] = ss; }
    __syncthreads();
    s  = as[0] + as[1] + as[2] + as[3];
    ss = ass[0] + ass[1] + ass[2] + ass[3];
    float mu  = s * (1.0f / 768.0f);
    float var = ss * (1.0f / 768.0f) - mu * mu;
    float rs  = rsqrtf(var + 1e-5f);
    u16* orow = out + (size_t)row * 768;
    orow[tid]       = f2bu((v0 - mu) * rs * g[tid]       + b[tid]);
    orow[tid + 256] = f2bu((v1 - mu) * rs * g[tid + 256] + b[tid + 256]);
    orow[tid + 512] = f2bu((v2 - mu) * rs * g[tid + 512] + b[tid + 512]);
}

// ---------------------------------------------------------------- split-K reduce (2 partials)
__global__ __launch_bounds__(256) void red2(
    const ushort4* __restrict__ P0, const ushort4* __restrict__ P1,
    const float* __restrict__ bias, const float4* __restrict__ res,
    float4* __restrict__ out)
{
    int i = blockIdx.x * 256 + threadIdx.x;
    int col = (i % 192) * 4;
    ushort4 a = P0[i], b = P1[i];
    float4 o = res ? res[i] : out[i];
    o.x += bias[col + 0] + b2f(a.x) + b2f(b.x);
    o.y += bias[col + 1] + b2f(a.y) + b2f(b.y);
    o.z += bias[col + 2] + b2f(a.z) + b2f(b.z);
    o.w += bias[col + 3] + b2f(a.w) + b2f(b.w);
    out[i] = o;
}

// ---------------------------------------------------------------- fused proj-reduce + LN2
__global__ __launch_bounds__(256) void red2_ln(
    const u16* __restrict__ P0, const u16* __restrict__ P1,
    const float* __restrict__ bias, const float* __restrict__ x,
    float* __restrict__ out,
    const float* __restrict__ g, const float* __restrict__ bb,
    u16* __restrict__ h)
{
    int row = blockIdx.x;
    int tid = threadIdx.x;
    size_t base = (size_t)row * 768;
    float v[3];
    float s = 0.f, ss = 0.f;
    #pragma unroll
    for (int j = 0; j < 3; ++j) {
        int col = tid + j * 256;
        size_t idx = base + col;
        float o = x[idx] + bias[col] + b2f(P0[idx]) + b2f(P1[idx]);
        out[idx] = o;
        v[j] = o;
        s += o; ss += o * o;
    }
    for (int off = 1; off < 64; off <<= 1) {
        s  += __shfl_xor(s, off, 64);
        ss += __shfl_xor(ss, off, 64);
    }
    __shared__ float as[4], ass[4];
    int wave = tid >> 6, lane = tid & 63;
    if (lane == 0) { as[wave] = s; ass[wave] = ss; }
    __syncthreads();
    s  = as[0] + as[1] + as[2] + as[3];
    ss = ass[0] + ass[1] + ass[2] + ass[3];
    float mu  = s * (1.0f / 768.0f);
    float var = ss * (1.0f / 768.0f) - mu * mu;
    float rs  = rsqrtf(var + 1e-5f);
    #pragma unroll
    for (int j = 0; j < 3; ++j) {
        int col = tid + j * 256;
        h[base + col] = f2bu((v[j] - mu) * rs * g[col] + bb[col]);
    }
}

// ---------------------------------------------------------------- GEMM 128x128, BK=64
// r3 config VERBATIM (measured best: FC1 ~65us, occ 49%, 0 conflicts).
// act: 0=none, 1=gelu, 2=scale cols<768 by 0.125 (Q pre-scale for attn; the
// 768 boundary is block-uniform since n0 is a multiple of 128).
// Charted and rejected: dbuf-drain (r1), BK32+vmcnt (r2), BM256 (r4),
// dbuf+counted-vmcnt (r5), 16x acc[2][2] (r6), 4x acc[4][4]+LB (r7),
// fp32-atomic split-K epilogue (r11), FC2 split-K=4 (r13, neutral).
__global__ __launch_bounds__(512, 4) void gemm_k64(
    const u16* __restrict__ A, int lda,
    const u16* __restrict__ B, int ldb,
    int K,
    const float* __restrict__ bias,
    const float* __restrict__ res,
    float* __restrict__ outf, u16* __restrict__ outb,
    u16* __restrict__ parts, size_t pstride,
    int ldc, int act, int splits)
{
    __shared__ u16 lsa[128 * 64];
    __shared__ u16 lsb[128 * 64];

    int tid  = threadIdx.x;
    int wave = tid >> 6, lane = tid & 63;
    int quad = lane >> 4, l16 = lane & 15;
    int wrow = (wave >> 1) * 32;     // 4 wave-rows x 32 rows
    int wcol = (wave & 1) * 64;      // 2 wave-cols x 64 cols

    int gx = gridDim.x;
    int nblk = gx * gridDim.y;
    int flat = blockIdx.y * gx + blockIdx.x;
    int d = (flat & 7) * (nblk >> 3) + (flat >> 3);
    int m0 = (d / gx) * 128, n0 = (d % gx) * 128;

    int Kper = K / splits;
    int kbeg = blockIdx.z * Kper;

    floatx4 acc[2][4];
    #pragma unroll
    for (int i = 0; i < 2; ++i)
        #pragma unroll
        for (int j = 0; j < 4; ++j)
            acc[i][j] = (floatx4){0.f, 0.f, 0.f, 0.f};

    int rsub = lane >> 3;
    int gc   = (lane & 7) ^ rsub;
    const u16* gA[2];
    const u16* gB[2];
    #pragma unroll
    for (int j = 0; j < 2; ++j) {
        int r = (j * 8 + wave) * 8 + rsub;
        gA[j] = A + (size_t)(m0 + r) * lda + kbeg + gc * 8;
        gB[j] = B + (size_t)(n0 + r) * ldb + kbeg + gc * 8;
    }

    int xq0 = ((quad)     ^ (l16 & 7)) * 8;
    int xq1 = ((quad + 4) ^ (l16 & 7)) * 8;

    for (int k0 = 0; k0 < Kper; k0 += 64) {
        __syncthreads();
        #pragma unroll
        for (int j = 0; j < 2; ++j) { load16(gA[j], &lsa[(j * 8 + wave) * 512]); gA[j] += 64; }
        #pragma unroll
        for (int j = 0; j < 2; ++j) { load16(gB[j], &lsb[(j * 8 + wave) * 512]); gB[j] += 64; }
        __syncthreads();

        short8 af[2], bfr[4];
        #pragma unroll
        for (int rb = 0; rb < 2; ++rb) af[rb]  = *(const short8*)&lsa[(wrow + rb * 16 + l16) * 64 + xq0];
        #pragma unroll
        for (int cb = 0; cb < 4; ++cb) bfr[cb] = *(const short8*)&lsb[(wcol + cb * 16 + l16) * 64 + xq0];
        #pragma unroll
        for (int rb = 0; rb < 2; ++rb)
            #pragma unroll
            for (int cb = 0; cb < 4; ++cb)
                acc[rb][cb] = __builtin_amdgcn_mfma_f32_16x16x32_bf16(af[rb], bfr[cb], acc[rb][cb], 0, 0, 0);
        #pragma unroll
        for (int rb = 0; rb < 2; ++rb) af[rb]  = *(const short8*)&lsa[(wrow + rb * 16 + l16) * 64 + xq1];
        #pragma unroll
        for (int cb = 0; cb < 4; ++cb) bfr[cb] = *(const short8*)&lsb[(wcol + cb * 16 + l16) * 64 + xq1];
        #pragma unroll
        for (int rb = 0; rb < 2; ++rb)
            #pragma unroll
            for (int cb = 0; cb < 4; ++cb)
                acc[rb][cb] = __builtin_amdgcn_mfma_f32_16x16x32_bf16(af[rb], bfr[cb], acc[rb][cb], 0, 0, 0);
    }

    u16* pdst = (splits > 1) ? parts + (size_t)blockIdx.z * pstride : nullptr;
    #pragma unroll
    for (int rb = 0; rb < 2; ++rb)
        #pragma unroll
        for (int cb = 0; cb < 4; ++cb)
            #pragma unroll
            for (int r = 0; r < 4; ++r) {
                int row = m0 + wrow + rb * 16 + quad * 4 + r;
                int col = n0 + wcol + cb * 16 + l16;
                float v = acc[rb][cb][r];
                if (splits > 1) {
                    pdst[(size_t)row * ldc + col] = f2bu(v);
                } else {
                    v += bias[col];
                    if (res) v += res[(size_t)row * ldc + col];
                    if (act == 1) v = gelu_f(v);
                    else if (act == 2 && col < 768) v *= 0.125f;   // Q pre-scale (exact: pow2)
                    if (outf) outf[(size_t)row * ldc + col] = v;
                    else      outb[(size_t)row * ldc + col] = f2bu(v);
                }
            }
}

// ---------------------------------------------------------------- fused attention
// qkv: bf16 [8*1024, 2304] with Q pre-scaled by 1/8; o: bf16 [8*1024, 768]
// grid (8 q-blocks of 128 rows, 96 b*h), block 256; wave = 32 q-rows.
// V-transpose writes packed to b32 (8 insts/thread, 2-lane/bank = free),
// softmax scale folded into Q upstream.
__global__ __launch_bounds__(256) void attn_fused(
    const u16* __restrict__ qkv, u16* __restrict__ o)
{
    const int N = 1024, C3 = 2304;
    int qb = blockIdx.x;
    int bh = blockIdx.y;
    int b = bh / 12, h = bh % 12;
    int tid = threadIdx.x, wave = tid >> 6, lane = tid & 63;
    int quad = lane >> 4, l16 = lane & 15;

    __shared__ u16 lk[64 * 64];       // K tile, XOR-swizzled [key][dchunk]
    __shared__ u16 lvt[64][72];       // V^T tile [d][key]
    __shared__ u16 lp[4][32][72];     // per-wave P [qrow(32)][key(64)]

    const size_t base = (size_t)b * N * C3;
    int q0 = qb * 128 + wave * 32;

    short8 qa[2][2];
    #pragma unroll
    for (int rb = 0; rb < 2; ++rb)
        #pragma unroll
        for (int ch = 0; ch < 2; ++ch)
            qa[rb][ch] = *(const short8*)&qkv[base + (size_t)(q0 + rb * 16 + l16) * C3 + h * 64 + ch * 32 + quad * 8];

    floatx4 oacc[2][4];
    #pragma unroll
    for (int i = 0; i < 2; ++i)
        #pragma unroll
        for (int j = 0; j < 4; ++j) oacc[i][j] = (floatx4){0.f, 0.f, 0.f, 0.f};
    float lsum[2][4] = {};

    for (int kt = 0; kt < N; kt += 64) {
        __syncthreads();
        #pragma unroll
        for (int i = 0; i < 2; ++i) {
            int idx = i * 2048 + wave * 512 + lane * 8;
            int r = idx >> 6;
            int gc = (lane & 7) ^ (r & 7);
            load16(&qkv[base + (size_t)(kt + r) * C3 + 768 + h * 64 + gc * 8], &lk[idx]);
        }
        {
            // packed V^T staging: thread owns keys {2kp, 2kp+1}, 8 d-values each;
            // writes 8 x b32 pairs (consecutive keys are adjacent u16 in a row).
            int kp = tid & 31;
            int dbase = (tid >> 5) * 8;
            const u16* vp0 = &qkv[base + (size_t)(kt + 2 * kp) * C3 + 1536 + h * 64 + dbase];
            const u16* vp1 = vp0 + C3;
            uint4 va = *(const uint4*)vp0;
            uint4 vb = *(const uint4*)vp1;
            const u16* e0 = (const u16*)&va;
            const u16* e1 = (const u16*)&vb;
            #pragma unroll
            for (int i = 0; i < 8; ++i) {
                unsigned pk = (unsigned)e0[i] | ((unsigned)e1[i] << 16);
                *(unsigned*)&lvt[dbase + i][2 * kp] = pk;
            }
        }
        __syncthreads();

        // S = Q K^T (Q pre-scaled) ; P = exp(S)
        #pragma unroll
        for (int kb = 0; kb < 4; ++kb) {
            int R = kb * 16 + l16;
            short8 b0 = *(short8*)&lk[R * 64 + ((quad ^ (R & 7)) * 8)];
            short8 b1 = *(short8*)&lk[R * 64 + (((quad + 4) ^ (R & 7)) * 8)];
            #pragma unroll
            for (int rb = 0; rb < 2; ++rb) {
                floatx4 c = (floatx4){0.f, 0.f, 0.f, 0.f};
                c = __builtin_amdgcn_mfma_f32_16x16x32_bf16(qa[rb][0], b0, c, 0, 0, 0);
                c = __builtin_amdgcn_mfma_f32_16x16x32_bf16(qa[rb][1], b1, c, 0, 0, 0);
                #pragma unroll
                for (int r = 0; r < 4; ++r) {
                    float p = __expf(c[r]);
                    lsum[rb][r] += p;
                    lp[wave][rb * 16 + quad * 4 + r][kb * 16 + l16] = f2bu(p);
                }
            }
        }

        // O += P V   (per-wave lp slice: same-wave RAW ordered by lgkmcnt)
        short8 pa[2][2];
        #pragma unroll
        for (int rb = 0; rb < 2; ++rb) {
            pa[rb][0] = *(short8*)&lp[wave][rb * 16 + l16][quad * 8];
            pa[rb][1] = *(short8*)&lp[wave][rb * 16 + l16][32 + quad * 8];
        }
        #pragma unroll
        for (int db = 0; db < 4; ++db) {
            short8 vb0 = *(short8*)&lvt[db * 16 + l16][quad * 8];
            short8 vb1 = *(short8*)&lvt[db * 16 + l16][32 + quad * 8];
            #pragma unroll
            for (int rb = 0; rb < 2; ++rb) {
                oacc[rb][db] = __builtin_amdgcn_mfma_f32_16x16x32_bf16(pa[rb][0], vb0, oacc[rb][db], 0, 0, 0);
                oacc[rb][db] = __builtin_amdgcn_mfma_f32_16x16x32_bf16(pa[rb][1], vb1, oacc[rb][db], 0, 0, 0);
            }
        }
    }

    #pragma unroll
    for (int rb = 0; rb < 2; ++rb)
        #pragma unroll
        for (int r = 0; r < 4; ++r)
            for (int off = 1; off < 16; off <<= 1)
                lsum[rb][r] += __shfl_xor(lsum[rb][r], off, 64);

    #pragma unroll
    for (int rb = 0; rb < 2; ++rb)
        #pragma unroll
        for (int db = 0; db < 4; ++db)
            #pragma unroll
            for (int r = 0; r < 4; ++r) {
                int row = q0 + rb * 16 + quad * 4 + r;
                int col = h * 64 + db * 16 + l16;
                o[(size_t)(b * N + row) * 768 + col] = f2bu(oacc[rb][db][r] / lsum[rb][r]);
            }
}

// ---------------------------------------------------------------- launch
extern "C" void kernel_launch(void* const* d_in, const int* in_sizes, int n_in,
                              void* d_out, int out_size, void* d_ws, size_t ws_size,
                              hipStream_t stream) {
    const float* x      = (const float*)d_in[0];
    const float* n1g    = (const float*)d_in[1];
    const float* n1b    = (const float*)d_in[2];
    const float* qkv_w  = (const float*)d_in[3];
    const float* qkv_b  = (const float*)d_in[4];
    const float* proj_w = (const float*)d_in[5];
    const float* proj_b = (const float*)d_in[6];
    const float* n2g    = (const float*)d_in[7];
    const float* n2b    = (const float*)d_in[8];
    const float* fc1_w  = (const float*)d_in[9];
    const float* fc1_b  = (const float*)d_in[10];
    const float* fc2_w  = (const float*)d_in[11];
    const float* fc2_b  = (const float*)d_in[12];
    float* out = (float*)d_out;

    const int T = 8192;
    char* ws = (char*)d_ws;
    u16* w_qkv  = (u16*)ws;               ws += (size_t)2304 * 768 * 2;
    u16* w_proj = (u16*)ws;               ws += (size_t)768 * 768 * 2;
    u16* w_fc1  = (u16*)ws;               ws += (size_t)3072 * 768 * 2;
    u16* w_fc2  = (u16*)ws;               ws += (size_t)768 * 3072 * 2;
    u16* h_buf  = (u16*)ws;               ws += (size_t)T * 768 * 2;
    u16* qkvbuf = (u16*)ws;               ws += (size_t)T * 2304 * 2;
    u16* o_buf  = (u16*)ws;               ws += (size_t)T * 768 * 2;
    u16* pbuf   = (u16*)ws;               ws += (size_t)T * 768 * 2;   // split-K partial #1
    u16* fc1out = qkvbuf;   // spans qkvbuf+o_buf (both dead at FC1 time)
    bool do_split = (size_t)(ws - (char*)d_ws) <= ws_size;
    size_t pstr = (size_t)(pbuf - h_buf);  // element stride: partial0(h_buf) -> partial1(pbuf)

    // fused: LN1 (8192 blocks) + all 4 weight cvts (6912 blocks)
    prep_fused<<<dim3(15104), 256, 0, stream>>>(
        x, n1g, n1b, h_buf,
        (const float4*)qkv_w,  (ushort4*)w_qkv,
        (const float4*)proj_w, (ushort4*)w_proj,
        (const float4*)fc1_w,  (ushort4*)w_fc1,
        (const float4*)fc2_w,  (ushort4*)w_fc2);

    // QKV (act=2: pre-scale Q columns by 1/8 for attention)
    gemm_k64<<<dim3(2304 / 128, T / 128), 512, 0, stream>>>(
        h_buf, 768, w_qkv, 768, 768, qkv_b, nullptr, nullptr, qkvbuf, nullptr, 0, 2304, 2, 1);
    // attention (128 q-rows/block)
    attn_fused<<<dim3(8, 96), 256, 0, stream>>>(qkvbuf, o_buf);
    // proj split-K=2 -> partials h_buf,pbuf; fused reduce+residual+LN2 -> out(fp32) + h(bf16)
    if (do_split) {
        gemm_k64<<<dim3(768 / 128, T / 128, 2), 512, 0, stream>>>(
            o_buf, 768, w_proj, 768, 768, proj_b, nullptr, nullptr, nullptr,
            h_buf, pstr, 768, 0, 2);
        red2_ln<<<dim3(T), 256, 0, stream>>>(
            h_buf, pbuf, proj_b, x, out, n2g, n2b, h_buf);
    } else {
        gemm_k64<<<dim3(768 / 128, T / 128), 512, 0, stream>>>(
            o_buf, 768, w_proj, 768, 768, proj_b, x, out, nullptr, nullptr, 0, 768, 0, 1);
        layernorm_bf16<<<dim3(T), 256, 0, stream>>>(out, n2g, n2b, h_buf);
    }
    // FC1 + GELU
    gemm_k64<<<dim3(3072 / 128, T / 128), 512, 0, stream>>>(
        h_buf, 768, w_fc1, 768, 768, fc1_b, nullptr, nullptr, fc1out, nullptr, 0, 3072, 1, 1);
    // FC2 + residual(out in place). Partials: h_buf (dead after FC1) + pbuf.
    if (do_split) {
        gemm_k64<<<dim3(768 / 128, T / 128, 2), 512, 0, stream>>>(
            fc1out, 3072, w_fc2, 3072, 3072, fc2_b, nullptr, nullptr, nullptr,
            h_buf, pstr, 768, 0, 2);
        red2<<<dim3(T * 768 / 4 / 256), 256, 0, stream>>>(
            (const ushort4*)h_buf, (const ushort4*)pbuf, fc2_b, nullptr, (float4*)out);
    } else {
        gemm_k64<<<dim3(768 / 128, T / 128), 512, 0, stream>>>(
            fc1out, 3072, w_fc2, 3072, 3072, fc2_b, out, out, nullptr, nullptr, 0, 768, 0, 1);
    }
}